// Round 14
// baseline (127.730 us; speedup 1.0000x reference)
//
#include <hip/hip_runtime.h>
#include <hip/hip_bf16.h>
#include <cstdint>

// B=2048, C=256, P=15, channels=512, groups=4 (128 ch each)
// r14 = r7 structure with k_stats FOLDED into k_pass1's tail:
//  - each block writes Part row, fences, bumps a device-scope counter;
//  - the last 64 arrivals (rank>=960) spin to 1024 then each reduces an
//    8-channel slice -> AB. Work is rank-sliced => bitwise deterministic.
//  - 1024 blocks @ 4/CU x 256 CU are exactly co-resident => spin is safe.
// p2: f32x4 output stores. wprep: also resets the counter (replay-safe).
#define EPS_ 1e-5f
#define NVALID_F 30720.0f

typedef __bf16 bf16x8 __attribute__((ext_vector_type(8)));
typedef float f32x16 __attribute__((ext_vector_type(16)));
typedef float f32x4 __attribute__((ext_vector_type(4)));
typedef unsigned short u16x8 __attribute__((ext_vector_type(8)));

__device__ __forceinline__ unsigned short f2bf(float f) {
  unsigned u = __float_as_uint(f);
  u += 0x7FFFu + ((u >> 16) & 1u);   // RNE
  return (unsigned short)(u >> 16);
}
__device__ __forceinline__ float bf2f(unsigned short h) {
  return __uint_as_float((unsigned)h << 16);
}

// ---- prologue: conv_w f32 [4][128][128] -> bf16 MFMA B-fragments; reset ctr ----
// Wf[g][mt][ks][lane][j] = w[g][o=mt*32+(lane&31)][i=ks*16+(lane>>5)*8+j]
__global__ void k_wprep(const float* __restrict__ w, unsigned short* __restrict__ wf,
                        int* __restrict__ ctr) {
  if (blockIdx.x == 0 && threadIdx.x == 0) *ctr = 0;   // fresh every call
  int q = blockIdx.x * 256 + threadIdx.x;  // 0..8191
  int l = q & 63, ks = (q >> 6) & 7, mt = (q >> 9) & 3, g = q >> 11;
  int o = mt * 32 + (l & 31);
  int i = ks * 16 + (l >> 5) * 8;
  const float* src = w + ((size_t)(g * 128 + o) * 128 + i);
  u16x8 v;
#pragma unroll
  for (int j = 0; j < 8; ++j) v[j] = f2bf(src[j]);
  *(u16x8*)(wf + (size_t)q * 8) = v;
}

// Build phase shared by both passes: stage 2 x-slabs through Yt union
// (coalesced), then overwrite Yt with bf16 Y = [xs | tmp].
__device__ __forceinline__ void build_Y_union(const float* __restrict__ x, int b0, int t,
                                              unsigned short* __restrict__ Yt) {
  {
    const f32x4* src = (const f32x4*)(x + (size_t)b0 * 3840);
    f32x4* dst = (f32x4*)Yt;
    for (int q = t; q < 1920; q += 256) dst[q] = src[q];
  }
  __syncthreads();
  float v[2][15];
  const float* xsf = (const float*)Yt;
#pragma unroll
  for (int bi = 0; bi < 2; ++bi)
#pragma unroll
    for (int p = 0; p < 15; ++p) v[bi][p] = xsf[bi * 3840 + t * 15 + p];
  __syncthreads();   // all reads done before Yt overwrite
#pragma unroll
  for (int bi = 0; bi < 2; ++bi) {
    float pm[5];
#pragma unroll
    for (int q = 0; q < 5; ++q)
      pm[q] = fmaxf(fmaxf(v[bi][3 * q], v[bi][3 * q + 1]), v[bi][3 * q + 2]);
    float mq[5];
    mq[0] = fmaxf(fmaxf(pm[1], pm[2]), fmaxf(pm[3], pm[4]));
    mq[1] = fmaxf(fmaxf(pm[0], pm[2]), fmaxf(pm[3], pm[4]));
    mq[2] = fmaxf(fmaxf(pm[0], pm[1]), fmaxf(pm[3], pm[4]));
    mq[3] = fmaxf(fmaxf(pm[0], pm[1]), fmaxf(pm[2], pm[4]));
    mq[4] = fmaxf(fmaxf(pm[0], pm[1]), fmaxf(pm[2], pm[3]));
    const int c0 = bi * 16;
#pragma unroll
    for (int p = 0; p < 15; ++p) {
      Yt[(c0 + p) * 520 + t] = f2bf(v[bi][p]);                      // xs -> ch 0..255
      Yt[(c0 + p) * 520 + 256 + t] = f2bf(mq[p / 3] - v[bi][p]);    // tmp -> ch 256..511
    }
    Yt[(c0 + 15) * 520 + t] = 0;        // pad rows: exact 0 (stats unaffected)
    Yt[(c0 + 15) * 520 + 256 + t] = 0;
  }
}

// ---- pass 1: GEMM + partials + tail-folded stats (last-64-arrivals) ----
__global__ __launch_bounds__(256, 4) void k_pass1(const float* __restrict__ x,
                                                  const unsigned short* __restrict__ wf,
                                                  float2* __restrict__ Part,
                                                  const float* __restrict__ gamma,
                                                  const float* __restrict__ beta,
                                                  float2* __restrict__ AB,
                                                  int* __restrict__ ctr) {
  __shared__ __align__(16) unsigned short Yt[32 * 520];
  const int t = threadIdx.x;
  const int b0 = blockIdx.x * 2;
  build_Y_union(x, b0, t, Yt);
  __syncthreads();

  const int lane = t & 63, g = t >> 6;
  const int l31 = lane & 31, lh = lane >> 5;
  const bf16x8* Wfv = (const bf16x8*)wf;

  bf16x8 bfr[8];
  const unsigned short* yrow = &Yt[l31 * 520 + g * 128 + lh * 8];
#pragma unroll
  for (int ks = 0; ks < 8; ++ks)
    bfr[ks] = *(const bf16x8*)(yrow + ks * 16);

  for (int mt = 0; mt < 4; ++mt) {
    bf16x8 wr[8];
#pragma unroll
    for (int ks = 0; ks < 8; ++ks)
      wr[ks] = Wfv[(size_t)((g * 4 + mt) * 8 + ks) * 64 + lane];
    f32x16 acc;
#pragma unroll
    for (int r = 0; r < 16; ++r) acc[r] = 0.f;
#pragma unroll
    for (int ks = 0; ks < 8; ++ks)
      acc = __builtin_amdgcn_mfma_f32_32x32x16_bf16(bfr[ks], wr[ks], acc, 0, 0, 0);
    float s = 0.f, s2 = 0.f;
#pragma unroll
    for (int r = 0; r < 16; ++r) { float vv = acc[r]; s += vv; s2 = fmaf(vv, vv, s2); }
    s += __shfl_xor(s, 32, 64);
    s2 += __shfl_xor(s2, 32, 64);
    const int ch = g * 128 + mt * 32 + l31;
    if (lane < 32) Part[(size_t)blockIdx.x * 512 + ch] = make_float2(s, s2);
  }

  // ---- arrival protocol: release Part row, take a rank ----
  __threadfence();                       // release: Part stores visible device-wide
  __shared__ int rank_s;
  if (t == 0)
    rank_s = atomicAdd(ctr, 1);          // device-scope RMW (m20)
  __syncthreads();
  const int rank = rank_s;
  if (rank < 960) return;                // not among last 64 arrivals

  // ---- last 64 arrivals: wait for all 1024, then reduce an 8-ch slice ----
  if (t == 0) {
    while (__hip_atomic_load(ctr, __ATOMIC_ACQUIRE, __HIP_MEMORY_SCOPE_AGENT) < 1024)
      __builtin_amdgcn_s_sleep(16);
  }
  __syncthreads();
  __threadfence();                       // acquire: all Part rows visible

  const int chb = (rank - 960) * 8;      // disjoint slices, rank-determined
  const int c = t & 7, r0 = t >> 3;
  float s = 0.f, s2 = 0.f;
  for (int k = 0; k < 32; ++k) {         // fixed order -> bitwise deterministic
    float2 vv = Part[(size_t)(r0 + 32 * k) * 512 + chb + c];
    s += vv.x; s2 += vv.y;
  }
  s += __shfl_xor(s, 8, 64);  s2 += __shfl_xor(s2, 8, 64);
  s += __shfl_xor(s, 16, 64); s2 += __shfl_xor(s2, 16, 64);
  s += __shfl_xor(s, 32, 64); s2 += __shfl_xor(s2, 32, 64);
  float2* red = (float2*)Yt;             // reuse LDS (GEMM done): [4][8]
  if ((t & 63) < 8) red[(t >> 6) * 8 + c] = make_float2(s, s2);
  __syncthreads();
  if (t < 8) {
    float S = 0.f, S2 = 0.f;
#pragma unroll
    for (int w = 0; w < 4; ++w) { S += red[w * 8 + t].x; S2 += red[w * 8 + t].y; }
    const float inv = 1.f / NVALID_F;
    float mean = S * inv;
    float var = fmaxf(S2 * inv - mean * mean, 0.f);
    float a = gamma[chb + t] * rsqrtf(var + EPS_);
    AB[chb + t] = make_float2(a, beta[chb + t] - mean * a);
  }
}

// ---- pass 2: recompute GEMM (x L3-warm), z-tile in LDS, finalize (f32x4) ----
__global__ __launch_bounds__(256, 4) void k_pass2(const float* __restrict__ x,
                                                  const unsigned short* __restrict__ wf,
                                                  const float2* __restrict__ AB,
                                                  float* __restrict__ out) {
  __shared__ __align__(16) unsigned short Yt[32 * 520];
  __shared__ float aArr[512], bArr[512];
  const int t = threadIdx.x;
  const int b0 = blockIdx.x * 2;

#pragma unroll
  for (int i = 0; i < 2; ++i) {
    int ch = i * 256 + t;
    float2 ab = AB[ch];
    aArr[ch] = ab.x; bArr[ch] = ab.y;
  }
  build_Y_union(x, b0, t, Yt);
  __syncthreads();

  {
    const int lane = t & 63, g = t >> 6;
    const int l31 = lane & 31, lh = lane >> 5;
    const bf16x8* Wfv = (const bf16x8*)wf;

    bf16x8 bfr[8];
    const unsigned short* yrow = &Yt[l31 * 520 + g * 128 + lh * 8];
#pragma unroll
    for (int ks = 0; ks < 8; ++ks)
      bfr[ks] = *(const bf16x8*)(yrow + ks * 16);

    // wave g reads+writes only cols [g*128, g*128+128): no inter-wave hazard
    for (int mt = 0; mt < 4; ++mt) {
      bf16x8 wr[8];
#pragma unroll
      for (int ks = 0; ks < 8; ++ks)
        wr[ks] = Wfv[(size_t)((g * 4 + mt) * 8 + ks) * 64 + lane];
      f32x16 acc;
#pragma unroll
      for (int r = 0; r < 16; ++r) acc[r] = 0.f;
#pragma unroll
      for (int ks = 0; ks < 8; ++ks)
        acc = __builtin_amdgcn_mfma_f32_32x32x16_bf16(bfr[ks], wr[ks], acc, 0, 0, 0);
      const int ch = g * 128 + mt * 32 + l31;
#pragma unroll
      for (int r = 0; r < 16; ++r) {
        int row = (r & 3) + 8 * (r >> 2) + 4 * lh;
        Yt[row * 520 + ch] = f2bf(acc[r]);   // pad rows written, never read
      }
    }
  }
  __syncthreads();   // z-tile visible to all waves

  // finalize: 15360 f32 (2 batches) as 3840 f32x4 stores
  f32x4* slab4 = (f32x4*)(out + (size_t)b0 * 7680);
#pragma unroll 5
  for (int it = 0; it < 15; ++it) {
    int q = it * 256 + t;         // f32x4 index 0..3839
    int e = q * 4;                // f32 index within the 2-batch slab
    int bi = e >= 7680;           // 7680 % 4 == 0 -> uniform across the 4 lanes
    int rbase = e - bi * 7680;
    f32x4 o;
#pragma unroll
    for (int j = 0; j < 4; ++j) {
      int r = rbase + j;
      int ch = r / 15, p = r - ch * 15;
      float f = bf2f(Yt[(bi * 16 + p) * 520 + ch]);
      o[j] = fmaxf(fmaf(f, aArr[ch], bArr[ch]), 0.f);
    }
    slab4[q] = o;
  }
}

extern "C" void kernel_launch(void* const* d_in, const int* in_sizes, int n_in,
                              void* d_out, int out_size, void* d_ws, size_t ws_size,
                              hipStream_t stream) {
  const float* x = (const float*)d_in[0];
  const float* cw = (const float*)d_in[1];
  // d_in[2] = conv_b: cancelled exactly by training-mode BN -> unused
  const float* gamma = (const float*)d_in[3];
  const float* beta = (const float*)d_in[4];

  unsigned short* wf = (unsigned short*)d_ws;             // 8192*8 bf16 = 128 KB
  float2* Part = (float2*)(wf + 65536);                   // 1024*512 float2 = 4 MB
  float2* AB = Part + (size_t)1024 * 512;                 // 512 float2 = 4 KB
  int* ctr = (int*)(AB + 512);                            // 4 B arrival counter

  hipLaunchKernelGGL(k_wprep, dim3(32), dim3(256), 0, stream, cw, wf, ctr);
  hipLaunchKernelGGL(k_pass1, dim3(1024), dim3(256), 0, stream, x, wf, Part,
                     gamma, beta, AB, ctr);
  hipLaunchKernelGGL(k_pass2, dim3(1024), dim3(256), 0, stream, x, wf, AB, (float*)d_out);
}

// Round 15
// 50.283 us; speedup vs baseline: 2.5402x; 2.5402x over previous
//
#include <hip/hip_runtime.h>
#include <hip/hip_bf16.h>
#include <cstdint>

// B=2048, C=256, P=15, channels=512, groups=4 (128 ch each)
// r15 = FINAL: r7's proven 4-kernel pipeline (best measured: 48.27us)
//  + r14's validated f32x4 finalize stores in pass2.
// Structure: wprep (w->bf16 MFMA frags) -> pass1 (GEMM, per-block stats
// partials) -> stats (fold to per-ch a,b) -> pass2 (recompute GEMM in LDS,
// fused BN+ReLU finalize). z never touches HBM; conv_b cancels in BN exactly.
// Lessons encoded: no grid.sync (r8: +95us), no device fences per block
// (r14: +79us), no atomic stats (r2: +57us), coalesced wf buffer (r9: +17us).
#define EPS_ 1e-5f
#define NVALID_F 30720.0f

typedef __bf16 bf16x8 __attribute__((ext_vector_type(8)));
typedef float f32x16 __attribute__((ext_vector_type(16)));
typedef float f32x4 __attribute__((ext_vector_type(4)));
typedef unsigned short u16x8 __attribute__((ext_vector_type(8)));

__device__ __forceinline__ unsigned short f2bf(float f) {
  unsigned u = __float_as_uint(f);
  u += 0x7FFFu + ((u >> 16) & 1u);   // RNE
  return (unsigned short)(u >> 16);
}
__device__ __forceinline__ float bf2f(unsigned short h) {
  return __uint_as_float((unsigned)h << 16);
}

// ---- prologue: conv_w f32 [4][128][128] -> bf16 MFMA B-fragments ----
// Wf[g][mt][ks][lane][j] = w[g][o=mt*32+(lane&31)][i=ks*16+(lane>>5)*8+j]
__global__ void k_wprep(const float* __restrict__ w, unsigned short* __restrict__ wf) {
  int q = blockIdx.x * 256 + threadIdx.x;  // 0..8191
  int l = q & 63, ks = (q >> 6) & 7, mt = (q >> 9) & 3, g = q >> 11;
  int o = mt * 32 + (l & 31);
  int i = ks * 16 + (l >> 5) * 8;
  const float* src = w + ((size_t)(g * 128 + o) * 128 + i);
  u16x8 v;
#pragma unroll
  for (int j = 0; j < 8; ++j) v[j] = f2bf(src[j]);
  *(u16x8*)(wf + (size_t)q * 8) = v;
}

// Build phase shared by both passes: stage 2 x-slabs through Yt union
// (coalesced), then overwrite Yt with bf16 Y = [xs | tmp].
__device__ __forceinline__ void build_Y_union(const float* __restrict__ x, int b0, int t,
                                              unsigned short* __restrict__ Yt) {
  {
    const f32x4* src = (const f32x4*)(x + (size_t)b0 * 3840);
    f32x4* dst = (f32x4*)Yt;
    for (int q = t; q < 1920; q += 256) dst[q] = src[q];
  }
  __syncthreads();
  float v[2][15];
  const float* xsf = (const float*)Yt;
#pragma unroll
  for (int bi = 0; bi < 2; ++bi)
#pragma unroll
    for (int p = 0; p < 15; ++p) v[bi][p] = xsf[bi * 3840 + t * 15 + p];
  __syncthreads();   // all reads done before Yt overwrite
#pragma unroll
  for (int bi = 0; bi < 2; ++bi) {
    float pm[5];
#pragma unroll
    for (int q = 0; q < 5; ++q)
      pm[q] = fmaxf(fmaxf(v[bi][3 * q], v[bi][3 * q + 1]), v[bi][3 * q + 2]);
    float mq[5];
    mq[0] = fmaxf(fmaxf(pm[1], pm[2]), fmaxf(pm[3], pm[4]));
    mq[1] = fmaxf(fmaxf(pm[0], pm[2]), fmaxf(pm[3], pm[4]));
    mq[2] = fmaxf(fmaxf(pm[0], pm[1]), fmaxf(pm[3], pm[4]));
    mq[3] = fmaxf(fmaxf(pm[0], pm[1]), fmaxf(pm[2], pm[4]));
    mq[4] = fmaxf(fmaxf(pm[0], pm[1]), fmaxf(pm[2], pm[3]));
    const int c0 = bi * 16;
#pragma unroll
    for (int p = 0; p < 15; ++p) {
      Yt[(c0 + p) * 520 + t] = f2bf(v[bi][p]);                      // xs -> ch 0..255
      Yt[(c0 + p) * 520 + 256 + t] = f2bf(mq[p / 3] - v[bi][p]);    // tmp -> ch 256..511
    }
    Yt[(c0 + 15) * 520 + t] = 0;        // pad rows: exact 0 (stats unaffected)
    Yt[(c0 + 15) * 520 + 256 + t] = 0;
  }
}

// ---- pass 1: GEMM, per-block (sum,sumsq) partials only ----
__global__ __launch_bounds__(256, 4) void k_pass1(const float* __restrict__ x,
                                                  const unsigned short* __restrict__ wf,
                                                  float2* __restrict__ Part) {
  __shared__ __align__(16) unsigned short Yt[32 * 520];
  const int t = threadIdx.x;
  const int b0 = blockIdx.x * 2;
  build_Y_union(x, b0, t, Yt);
  __syncthreads();

  const int lane = t & 63, g = t >> 6;
  const int l31 = lane & 31, lh = lane >> 5;
  const bf16x8* Wfv = (const bf16x8*)wf;

  bf16x8 bfr[8];
  const unsigned short* yrow = &Yt[l31 * 520 + g * 128 + lh * 8];
#pragma unroll
  for (int ks = 0; ks < 8; ++ks)
    bfr[ks] = *(const bf16x8*)(yrow + ks * 16);

  for (int mt = 0; mt < 4; ++mt) {
    bf16x8 wr[8];
#pragma unroll
    for (int ks = 0; ks < 8; ++ks)
      wr[ks] = Wfv[(size_t)((g * 4 + mt) * 8 + ks) * 64 + lane];
    f32x16 acc;
#pragma unroll
    for (int r = 0; r < 16; ++r) acc[r] = 0.f;
#pragma unroll
    for (int ks = 0; ks < 8; ++ks)
      acc = __builtin_amdgcn_mfma_f32_32x32x16_bf16(bfr[ks], wr[ks], acc, 0, 0, 0);
    float s = 0.f, s2 = 0.f;
#pragma unroll
    for (int r = 0; r < 16; ++r) { float vv = acc[r]; s += vv; s2 = fmaf(vv, vv, s2); }
    s += __shfl_xor(s, 32, 64);
    s2 += __shfl_xor(s2, 32, 64);
    const int ch = g * 128 + mt * 32 + l31;
    if (lane < 32) Part[(size_t)blockIdx.x * 512 + ch] = make_float2(s, s2);
  }
}

// ---- stats: 64 blocks x 8 ch; dense 64B-line reads of Part ----
__global__ void k_stats(const float2* __restrict__ Part,
                        const float* __restrict__ gamma, const float* __restrict__ beta,
                        float2* __restrict__ AB) {
  const int t = threadIdx.x;
  const int chb = blockIdx.x * 8;
  const int c = t & 7, r0 = t >> 3;
  float s = 0.f, s2 = 0.f;
  for (int k = 0; k < 32; ++k) {
    float2 vv = Part[(size_t)(r0 + 32 * k) * 512 + chb + c];
    s += vv.x; s2 += vv.y;
  }
  s += __shfl_xor(s, 8, 64);  s2 += __shfl_xor(s2, 8, 64);
  s += __shfl_xor(s, 16, 64); s2 += __shfl_xor(s2, 16, 64);
  s += __shfl_xor(s, 32, 64); s2 += __shfl_xor(s2, 32, 64);
  __shared__ float2 red[4][8];
  if ((t & 63) < 8) red[t >> 6][c] = make_float2(s, s2);
  __syncthreads();
  if (t < 8) {
    float S = 0.f, S2 = 0.f;
#pragma unroll
    for (int w = 0; w < 4; ++w) { S += red[w][t].x; S2 += red[w][t].y; }
    const float inv = 1.f / NVALID_F;
    float mean = S * inv;
    float var = fmaxf(S2 * inv - mean * mean, 0.f);
    float a = gamma[chb + t] * rsqrtf(var + EPS_);
    AB[chb + t] = make_float2(a, beta[chb + t] - mean * a);
  }
}

// ---- pass 2: recompute GEMM, z-tile in LDS, finalize (f32x4 stores) ----
__global__ __launch_bounds__(256, 4) void k_pass2(const float* __restrict__ x,
                                                  const unsigned short* __restrict__ wf,
                                                  const float2* __restrict__ AB,
                                                  float* __restrict__ out) {
  __shared__ __align__(16) unsigned short Yt[32 * 520];
  __shared__ float aArr[512], bArr[512];
  const int t = threadIdx.x;
  const int b0 = blockIdx.x * 2;

#pragma unroll
  for (int i = 0; i < 2; ++i) {
    int ch = i * 256 + t;
    float2 ab = AB[ch];
    aArr[ch] = ab.x; bArr[ch] = ab.y;
  }
  build_Y_union(x, b0, t, Yt);
  __syncthreads();

  {
    const int lane = t & 63, g = t >> 6;
    const int l31 = lane & 31, lh = lane >> 5;
    const bf16x8* Wfv = (const bf16x8*)wf;

    bf16x8 bfr[8];
    const unsigned short* yrow = &Yt[l31 * 520 + g * 128 + lh * 8];
#pragma unroll
    for (int ks = 0; ks < 8; ++ks)
      bfr[ks] = *(const bf16x8*)(yrow + ks * 16);

    // wave g reads+writes only cols [g*128, g*128+128): no inter-wave hazard
    for (int mt = 0; mt < 4; ++mt) {
      bf16x8 wr[8];
#pragma unroll
      for (int ks = 0; ks < 8; ++ks)
        wr[ks] = Wfv[(size_t)((g * 4 + mt) * 8 + ks) * 64 + lane];
      f32x16 acc;
#pragma unroll
      for (int r = 0; r < 16; ++r) acc[r] = 0.f;
#pragma unroll
      for (int ks = 0; ks < 8; ++ks)
        acc = __builtin_amdgcn_mfma_f32_32x32x16_bf16(bfr[ks], wr[ks], acc, 0, 0, 0);
      const int ch = g * 128 + mt * 32 + l31;
#pragma unroll
      for (int r = 0; r < 16; ++r) {
        int row = (r & 3) + 8 * (r >> 2) + 4 * lh;
        Yt[row * 520 + ch] = f2bf(acc[r]);   // pad rows written, never read
      }
    }
  }
  __syncthreads();   // z-tile visible to all waves

  // finalize: 15360 f32 (2 batches) as 3840 f32x4 stores (validated r14)
  f32x4* slab4 = (f32x4*)(out + (size_t)b0 * 7680);
#pragma unroll 5
  for (int it = 0; it < 15; ++it) {
    int q = it * 256 + t;         // f32x4 index 0..3839
    int e = q * 4;                // f32 index within the 2-batch slab
    int bi = e >= 7680;           // 7680 % 4 == 0 -> uniform across the 4 lanes
    int rbase = e - bi * 7680;
    f32x4 o;
#pragma unroll
    for (int j = 0; j < 4; ++j) {
      int r = rbase + j;
      int ch = r / 15, p = r - ch * 15;
      float f = bf2f(Yt[(bi * 16 + p) * 520 + ch]);
      o[j] = fmaxf(fmaf(f, aArr[ch], bArr[ch]), 0.f);
    }
    slab4[q] = o;
  }
}

extern "C" void kernel_launch(void* const* d_in, const int* in_sizes, int n_in,
                              void* d_out, int out_size, void* d_ws, size_t ws_size,
                              hipStream_t stream) {
  const float* x = (const float*)d_in[0];
  const float* cw = (const float*)d_in[1];
  // d_in[2] = conv_b: cancelled exactly by training-mode BN -> unused
  const float* gamma = (const float*)d_in[3];
  const float* beta = (const float*)d_in[4];

  unsigned short* wf = (unsigned short*)d_ws;             // 8192*8 bf16 = 128 KB
  float2* Part = (float2*)(wf + 65536);                   // 1024*512 float2 = 4 MB
  float2* AB = Part + (size_t)1024 * 512;                 // 512 float2 = 4 KB

  hipLaunchKernelGGL(k_wprep, dim3(32), dim3(256), 0, stream, cw, wf);
  hipLaunchKernelGGL(k_pass1, dim3(1024), dim3(256), 0, stream, x, wf, Part);
  hipLaunchKernelGGL(k_stats, dim3(64), dim3(256), 0, stream, Part, gamma, beta, AB);
  hipLaunchKernelGGL(k_pass2, dim3(1024), dim3(256), 0, stream, x, wf, AB, (float*)d_out);
}